// Round 6
// baseline (461.869 us; speedup 1.0000x reference)
//
#include <hip/hip_runtime.h>

#define T_TOK 2048
#define S_LEN 1024
#define HIDN  2880
#define NHQ   64
#define NHKV  8
#define DH    64
#define QSZ   4096
#define KVSZ  512
#define WIN   128
#define NQKV  5120
#define NOPAD 2944

typedef __attribute__((ext_vector_type(4))) float f32x4;
typedef __attribute__((ext_vector_type(8))) short bf16x8;
typedef __attribute__((ext_vector_type(4))) short s16x4;

__device__ __forceinline__ unsigned short f2bf(float f) {
  unsigned u = __float_as_uint(f);
  u += 0x7fffu + ((u >> 16) & 1u);
  return (unsigned short)(u >> 16);
}
__device__ __forceinline__ float bf2f(unsigned short s) {
  return __uint_as_float(((unsigned)s) << 16);
}
__device__ __forceinline__ void ld_g2l16(const void* g, void* l) {
  __builtin_amdgcn_global_load_lds(
      (const __attribute__((address_space(1))) unsigned int*)g,
      (__attribute__((address_space(3))) unsigned int*)l, 16, 0, 0);
}

// ---------- merged prep: hidden fp32->bf16 + Wq/Wk/Wv transpose ----------
#define NB_CONV 2880
#define NB_WQ   5760
#define NB_WK   720

__device__ __forceinline__ void transpose_tile(
    const float* __restrict__ W, unsigned short* __restrict__ WT,
    int N, int lbid, float (*tile)[72])
{
  const int tid = threadIdx.x;
  const int nbx = N >> 6;
  const int nb = (lbid % nbx) * 64;
  const int kb = (lbid / nbx) * 32;
  const int kk = tid >> 3;
  const int n8 = (tid & 7) * 8;
  const float* src = W + (size_t)(kb + kk) * N + nb + n8;
  *(f32x4*)&tile[kk][n8]     = *(const f32x4*)(src);
  *(f32x4*)&tile[kk][n8 + 4] = *(const f32x4*)(src + 4);
  __syncthreads();
  const int n  = tid & 63;
  const int k8 = (tid >> 6) * 8;
  bf16x8 p;
  #pragma unroll
  for (int j = 0; j < 8; ++j) p[j] = (short)f2bf(tile[k8 + j][n]);
  *(bf16x8*)(WT + (size_t)(nb + n) * HIDN + kb + k8) = p;
}

__global__ __launch_bounds__(256) void prep_kernel(
    const float* __restrict__ hidden, unsigned short* __restrict__ hbf,
    const float* __restrict__ Wq, const float* __restrict__ Wk,
    const float* __restrict__ Wv, unsigned short* __restrict__ WT)
{
  __shared__ float tile[32][72];
  const int bid = blockIdx.x;
  if (bid < NB_CONV) {
    const size_t off = ((size_t)bid * 256 + threadIdx.x) * 8;
    const f32x4 a = *(const f32x4*)(hidden + off);
    const f32x4 b = *(const f32x4*)(hidden + off + 4);
    bf16x8 p;
    p[0] = (short)f2bf(a[0]); p[1] = (short)f2bf(a[1]);
    p[2] = (short)f2bf(a[2]); p[3] = (short)f2bf(a[3]);
    p[4] = (short)f2bf(b[0]); p[5] = (short)f2bf(b[1]);
    p[6] = (short)f2bf(b[2]); p[7] = (short)f2bf(b[3]);
    *(bf16x8*)(hbf + off) = p;
  } else if (bid < NB_CONV + NB_WQ) {
    transpose_tile(Wq, WT, QSZ, bid - NB_CONV, tile);
  } else if (bid < NB_CONV + NB_WQ + NB_WK) {
    transpose_tile(Wk, WT + (size_t)QSZ * HIDN, KVSZ,
                   bid - NB_CONV - NB_WQ, tile);
  } else {
    transpose_tile(Wv, WT + (size_t)(QSZ + KVSZ) * HIDN, KVSZ,
                   bid - NB_CONV - NB_WQ - NB_WK, tile);
  }
}

// ---- Wo [K=4096][N=2880] fp32 -> WT [2944 pad][4096] bf16 (edge-guarded) -
__global__ __launch_bounds__(256) void transpose_w(
    const float* __restrict__ W, unsigned short* __restrict__ WT,
    int K, int N)
{
  __shared__ float tile[32][72];
  const int tid = threadIdx.x;
  const int nb = blockIdx.x * 64;
  const int kb = blockIdx.y * 32;
  const int kk = tid >> 3;
  const int n8 = (tid & 7) * 8;
  if (nb + 64 <= N) {
    const float* src = W + (size_t)(kb + kk) * N + nb + n8;
    *(f32x4*)&tile[kk][n8]     = *(const f32x4*)(src);
    *(f32x4*)&tile[kk][n8 + 4] = *(const f32x4*)(src + 4);
  } else {
    #pragma unroll
    for (int u = 0; u < 8; ++u)
      tile[kk][n8 + u] = (nb + n8 + u < N)
          ? W[(size_t)(kb + kk) * N + nb + n8 + u] : 0.f;
  }
  __syncthreads();
  const int n  = tid & 63;
  const int k8 = (tid >> 6) * 8;
  bf16x8 p;
  #pragma unroll
  for (int j = 0; j < 8; ++j) p[j] = (short)f2bf(tile[k8 + j][n]);
  *(bf16x8*)(WT + (size_t)(nb + n) * K + kb + k8) = p;
}

// rope+bias epilogue for a 64-col group. C/D: col=lane&15, row=(lane>>4)*4+i.
__device__ __forceinline__ void rope_epilogue(
    f32x4 acc[4][4], const float* __restrict__ bias,
    const int* __restrict__ pos, unsigned short* __restrict__ outp,
    int outStride, int colbase, int rowbase, int lane)
{
  const int fr = lane & 15;
  const int r4 = (lane >> 4) * 4;
  const float invf0 = exp2f((float)fr        * (-17.19460283f / 32.0f));
  const float invf1 = exp2f((float)(fr + 16) * (-17.19460283f / 32.0f));
  #pragma unroll
  for (int mt = 0; mt < 4; ++mt) {
    #pragma unroll
    for (int i = 0; i < 4; ++i) {
      const int m = rowbase + mt * 16 + r4 + i;
      const float p = (float)pos[m];
      #pragma unroll
      for (int ntp = 0; ntp < 2; ++ntp) {
        float sv, cv;
        __sincosf(p * (ntp ? invf1 : invf0), &sv, &cv);
        const int c1 = colbase + ntp * 16 + fr;
        const float x1 = acc[mt][ntp][i]     + bias[c1];
        const float x2 = acc[mt][ntp + 2][i] + bias[c1 + 32];
        outp[(size_t)m * outStride + c1]      = f2bf(x1 * cv - x2 * sv);
        outp[(size_t)m * outStride + c1 + 32] = f2bf(x1 * sv + x2 * cv);
      }
    }
  }
}

// ---- QKV GEMM: 64m x 128n, 2 waves, BK=32, DOUBLE-BUFFERED LDS ----------
// Prefetch-after-barrier: loads for iter it+1 are issued right after the
// barrier of iter it and drained only at the barrier of iter it+1 — a full
// compute phase of fly time. 4-chunk xor swizzle keeps g2l dests
// wave-contiguous and fragment reads 2-way (free) on banks.
__global__ __launch_bounds__(128) void gemm_qkv(
    const unsigned short* __restrict__ A, const unsigned short* __restrict__ BT,
    const float* __restrict__ bq, const float* __restrict__ bk,
    const float* __restrict__ bv, const int* __restrict__ pos,
    unsigned short* __restrict__ qb, unsigned short* __restrict__ kb,
    unsigned short* __restrict__ vT)
{
  __shared__ unsigned short As[2][64 * 32];
  __shared__ unsigned short Bs[2][128 * 32];
  const int tid  = threadIdx.x;
  const int lane = tid & 63;
  const int wid  = tid >> 6;
  const int m0 = blockIdx.y * 64;
  const int n0 = blockIdx.x * 128;
  const int wn = wid * 64;
  const int fr = lane & 15;
  const int fq = lane >> 4;

  f32x4 acc[4][4];
  #pragma unroll
  for (int i = 0; i < 4; ++i)
    #pragma unroll
    for (int j = 0; j < 4; ++j) acc[i][j] = (f32x4){0.f, 0.f, 0.f, 0.f};

  const int rsub  = tid >> 2;            // 0..31
  const int cslot = tid & 3;
  const int cg    = cslot ^ (rsub & 3);  // global 8-el chunk for xor layout
  const unsigned short* Ap = A  + (size_t)(m0 + rsub) * HIDN + cg * 8;
  const unsigned short* Bp = BT + (size_t)(n0 + rsub) * HIDN + cg * 8;
  const size_t rstep = (size_t)32 * HIDN;

  auto stage = [&](int b, int k0) {
    #pragma unroll
    for (int i = 0; i < 2; ++i)
      ld_g2l16(Ap + i * rstep + k0, &As[b][i * 1024 + tid * 8]);
    #pragma unroll
    for (int i = 0; i < 4; ++i)
      ld_g2l16(Bp + i * rstep + k0, &Bs[b][i * 1024 + tid * 8]);
  };

  stage(0, 0);
  const int NIT = HIDN / 32;             // 90
  for (int it = 0; it < NIT; ++it) {
    __syncthreads();                     // drains buf[it&1] loads (1 iter old)
    if (it + 1 < NIT) stage((it + 1) & 1, (it + 1) * 32);
    const unsigned short* as = As[it & 1];
    const unsigned short* bs = Bs[it & 1];
    bf16x8 af[4], bfr[4];
    #pragma unroll
    for (int mt = 0; mt < 4; ++mt) {
      const int R = mt * 16 + fr;
      af[mt] = *(const bf16x8*)(as + R * 32 + ((fq ^ (R & 3)) << 3));
    }
    #pragma unroll
    for (int nt = 0; nt < 4; ++nt) {
      const int R = wn + nt * 16 + fr;
      bfr[nt] = *(const bf16x8*)(bs + R * 32 + ((fq ^ (R & 3)) << 3));
    }
    #pragma unroll
    for (int mt = 0; mt < 4; ++mt)
      #pragma unroll
      for (int nt = 0; nt < 4; ++nt)
        acc[mt][nt] = __builtin_amdgcn_mfma_f32_16x16x32_bf16(
            af[mt], bfr[nt], acc[mt][nt], 0, 0, 0);
  }

  const int r4 = (lane >> 4) * 4;
  if (n0 < QSZ) {
    rope_epilogue(acc, bq, pos, qb, QSZ, n0 + wn, m0, lane);
  } else if (n0 < QSZ + KVSZ) {
    rope_epilogue(acc, bk, pos, kb, KVSZ, n0 - QSZ + wn, m0, lane);
  } else {
    #pragma unroll
    for (int nt = 0; nt < 4; ++nt) {
      const int vrow = n0 - (QSZ + KVSZ) + wn + nt * 16 + fr;
      const float bvv = bv[vrow];
      #pragma unroll
      for (int mt = 0; mt < 4; ++mt) {
        const int mb = m0 + mt * 16 + r4;
        s16x4 p;
        p[0] = (short)f2bf(acc[mt][nt][0] + bvv);
        p[1] = (short)f2bf(acc[mt][nt][1] + bvv);
        p[2] = (short)f2bf(acc[mt][nt][2] + bvv);
        p[3] = (short)f2bf(acc[mt][nt][3] + bvv);
        *(s16x4*)(vT + (size_t)vrow * T_TOK + mb) = p;
      }
    }
  }
}

// ---- O-proj GEMM: 64m x 128n, 2 waves, BK=32, double-buffered, f32 out ---
__global__ __launch_bounds__(128) void gemm_o(
    const unsigned short* __restrict__ A, const unsigned short* __restrict__ BT,
    const float* __restrict__ bias, float* __restrict__ C)
{
  __shared__ unsigned short As[2][64 * 32];
  __shared__ unsigned short Bs[2][128 * 32];
  const int tid  = threadIdx.x;
  const int lane = tid & 63;
  const int wid  = tid >> 6;
  const int m0 = blockIdx.y * 64;
  const int n0 = blockIdx.x * 128;
  const int wn = wid * 64;
  const int fr = lane & 15;
  const int fq = lane >> 4;

  f32x4 acc[4][4];
  #pragma unroll
  for (int i = 0; i < 4; ++i)
    #pragma unroll
    for (int j = 0; j < 4; ++j) acc[i][j] = (f32x4){0.f, 0.f, 0.f, 0.f};

  const int rsub  = tid >> 2;
  const int cslot = tid & 3;
  const int cg    = cslot ^ (rsub & 3);
  const unsigned short* Ap = A  + (size_t)(m0 + rsub) * QSZ + cg * 8;
  const unsigned short* Bp = BT + (size_t)(n0 + rsub) * QSZ + cg * 8;
  const size_t rstep = (size_t)32 * QSZ;

  auto stage = [&](int b, int k0) {
    #pragma unroll
    for (int i = 0; i < 2; ++i)
      ld_g2l16(Ap + i * rstep + k0, &As[b][i * 1024 + tid * 8]);
    #pragma unroll
    for (int i = 0; i < 4; ++i)
      ld_g2l16(Bp + i * rstep + k0, &Bs[b][i * 1024 + tid * 8]);
  };

  stage(0, 0);
  const int NIT = QSZ / 32;              // 128
  for (int it = 0; it < NIT; ++it) {
    __syncthreads();
    if (it + 1 < NIT) stage((it + 1) & 1, (it + 1) * 32);
    const unsigned short* as = As[it & 1];
    const unsigned short* bs = Bs[it & 1];
    bf16x8 af[4], bfr[4];
    #pragma unroll
    for (int mt = 0; mt < 4; ++mt) {
      const int R = mt * 16 + fr;
      af[mt] = *(const bf16x8*)(as + R * 32 + ((fq ^ (R & 3)) << 3));
    }
    #pragma unroll
    for (int nt = 0; nt < 4; ++nt) {
      const int R = wn + nt * 16 + fr;
      bfr[nt] = *(const bf16x8*)(bs + R * 32 + ((fq ^ (R & 3)) << 3));
    }
    #pragma unroll
    for (int mt = 0; mt < 4; ++mt)
      #pragma unroll
      for (int nt = 0; nt < 4; ++nt)
        acc[mt][nt] = __builtin_amdgcn_mfma_f32_16x16x32_bf16(
            af[mt], bfr[nt], acc[mt][nt], 0, 0, 0);
  }

  const int r4 = (lane >> 4) * 4;
  #pragma unroll
  for (int nt = 0; nt < 4; ++nt) {
    const int n = n0 + wn + nt * 16 + fr;
    if (n >= HIDN) continue;
    const float bvv = bias[n];
    #pragma unroll
    for (int mt = 0; mt < 4; ++mt) {
      const int mb = m0 + mt * 16 + r4;
      #pragma unroll
      for (int i = 0; i < 4; ++i)
        C[(size_t)(mb + i) * HIDN + n] = acc[mt][nt][i] + bvv;
    }
  }
}

// ---------------- MFMA sliding-window GQA attention, 2 heads/block --------
__global__ __launch_bounds__(256, 3) void attn_kernel(
    const unsigned short* __restrict__ q, const unsigned short* __restrict__ k,
    const unsigned short* __restrict__ vT, unsigned short* __restrict__ o)
{
  __shared__ unsigned short lds[26624];     // 53,248 B -> 3 blocks/CU
  unsigned short* Ks = lds;                 // [192][72]
  unsigned short* Vt = lds;                 // [64][200] (over Ks)
  unsigned short* Ps = lds + 13824;         // [64][200]

  const int tid  = threadIdx.x;
  const int lane = tid & 63;
  const int wid  = tid >> 6;
  const int sq0  = blockIdx.x * 64;
  const int hp   = blockIdx.y;
  const int b    = blockIdx.z;
  const int h0   = hp * 2;
  const int kvh  = hp >> 2;
  const int kp0  = sq0 - WIN;

  const int fr = lane & 15;
  const int fk = (lane >> 4) * 8;
  const int qw = wid * 16;

  bf16x8 qf[2][2];
  {
    const size_t qrow = (size_t)(b * S_LEN + sq0 + qw + fr) * QSZ;
    #pragma unroll
    for (int hh = 0; hh < 2; ++hh)
      #pragma unroll
      for (int ks2 = 0; ks2 < 2; ++ks2)
        qf[hh][ks2] = *(const bf16x8*)(q + qrow + (h0 + hh) * DH + ks2 * 32 + fk);
  }

  #pragma unroll
  for (int j = 0; j < 6; ++j) {
    const int c  = tid + j * 256;
    const int kr = c >> 3, dc = (c & 7) * 8;
    int tok = b * S_LEN + kp0 + kr;
    if (tok < 0) tok = 0;                   // masked later
    const bf16x8 vv = *(const bf16x8*)(k + (size_t)tok * KVSZ + kvh * DH + dc);
    *(bf16x8*)&Ks[kr * 72 + dc] = vv;
  }
  __syncthreads();

  f32x4 S0[12], S1[12];
  #pragma unroll
  for (int i = 0; i < 12; ++i) {
    S0[i] = (f32x4){0.f, 0.f, 0.f, 0.f};
    S1[i] = (f32x4){0.f, 0.f, 0.f, 0.f};
  }
  #pragma unroll
  for (int ks2 = 0; ks2 < 2; ++ks2) {
    #pragma unroll
    for (int nt = 0; nt < 12; ++nt) {
      const bf16x8 bfr = *(const bf16x8*)&Ks[(nt * 16 + fr) * 72 + ks2 * 32 + fk];
      S0[nt] = __builtin_amdgcn_mfma_f32_16x16x32_bf16(qf[0][ks2], bfr, S0[nt], 0, 0, 0);
      S1[nt] = __builtin_amdgcn_mfma_f32_16x16x32_bf16(qf[1][ks2], bfr, S1[nt], 0, 0, 0);
    }
  }

  const int qbase = sq0 + qw + ((lane >> 4) << 2);
  float ls0[4] = {0.f, 0.f, 0.f, 0.f};
  float ls1[4] = {0.f, 0.f, 0.f, 0.f};
  #pragma unroll
  for (int nt = 0; nt < 12; ++nt) {
    const int jpos = kp0 + nt * 16 + fr;
    #pragma unroll
    for (int i = 0; i < 4; ++i) {
      const int qa = qbase + i;
      const bool valid = (jpos >= 0) && (jpos <= qa) && (jpos >= qa - WIN);
      const float e0 = valid ? __expf(S0[nt][i] * 0.125f) : 0.f;
      const float e1 = valid ? __expf(S1[nt][i] * 0.125f) : 0.f;
      S0[nt][i] = e0; ls0[i] += e0;
      S1[nt][i] = e1; ls1[i] += e1;
    }
  }
  #pragma unroll
  for (int off = 1; off < 16; off <<= 1)
    #pragma unroll
    for (int i = 0; i < 4; ++i) {
      ls0[i] += __shfl_xor(ls0[i], off, 64);
      ls1[i] += __shfl_xor(ls1[i], off, 64);
    }
  float inv0[4], inv1[4];
  #pragma unroll
  for (int i = 0; i < 4; ++i) {
    inv0[i] = 1.0f / ls0[i];
    inv1[i] = 1.0f / ls1[i];
  }
  __syncthreads();   // all waves done reading Ks

  #pragma unroll
  for (int nt = 0; nt < 12; ++nt)
    #pragma unroll
    for (int i = 0; i < 4; ++i)
      Ps[(qbase - sq0 + i) * 200 + nt * 16 + fr] = f2bf(S0[nt][i]);
  if (kp0 >= 0) {
    #pragma unroll
    for (int j = 0; j < 6; ++j) {
      const int c  = tid + j * 256;
      const int dr = c / 24, kc = (c % 24) * 8;
      const bf16x8 vv = *(const bf16x8*)(
          vT + (size_t)(kvh * DH + dr) * T_TOK + b * S_LEN + kp0 + kc);
      *(bf16x8*)&Vt[dr * 200 + kc] = vv;
    }
  } else {
    #pragma unroll
    for (int j = 0; j < 6; ++j) {
      const int c  = tid + j * 256;
      const int dr = c / 24, kc = (c % 24) * 8;
      bf16x8 vv;
      #pragma unroll
      for (int u = 0; u < 8; ++u) {
        int col = b * S_LEN + kp0 + kc + u;
        if (col < 0) col = 0;               // p==0 there
        vv[u] = (short)vT[(size_t)(kvh * DH + dr) * T_TOK + col];
      }
      *(bf16x8*)&Vt[dr * 200 + kc] = vv;
    }
  }
  __syncthreads();

  {
    f32x4 O[4];
    #pragma unroll
    for (int i = 0; i < 4; ++i) O[i] = (f32x4){0.f, 0.f, 0.f, 0.f};
    #pragma unroll
    for (int ks2 = 0; ks2 < 6; ++ks2) {
      const bf16x8 pa = *(const bf16x8*)&Ps[(qw + fr) * 200 + ks2 * 32 + fk];
      #pragma unroll
      for (int nt = 0; nt < 4; ++nt) {
        const bf16x8 vb = *(const bf16x8*)&Vt[(nt * 16 + fr) * 200 + ks2 * 32 + fk];
        O[nt] = __builtin_amdgcn_mfma_f32_16x16x32_bf16(pa, vb, O[nt], 0, 0, 0);
      }
    }
    #pragma unroll
    for (int nt = 0; nt < 4; ++nt)
      #pragma unroll
      for (int i = 0; i < 4; ++i)
        o[(size_t)(b * S_LEN + qbase + i) * QSZ + h0 * DH + nt * 16 + fr] =
            f2bf(O[nt][i] * inv0[i]);
  }
  __syncthreads();   // all waves done reading P0

  #pragma unroll
  for (int nt = 0; nt < 12; ++nt)
    #pragma unroll
    for (int i = 0; i < 4; ++i)
      Ps[(qbase - sq0 + i) * 200 + nt * 16 + fr] = f2bf(S1[nt][i]);
  __syncthreads();

  {
    f32x4 O[4];
    #pragma unroll
    for (int i = 0; i < 4; ++i) O[i] = (f32x4){0.f, 0.f, 0.f, 0.f};
    #pragma unroll
    for (int ks2 = 0; ks2 < 6; ++ks2) {
      const bf16x8 pa = *(const bf16x8*)&Ps[(qw + fr) * 200 + ks2 * 32 + fk];
      #pragma unroll
      for (int nt = 0; nt < 4; ++nt) {
        const bf16x8 vb = *(const bf16x8*)&Vt[(nt * 16 + fr) * 200 + ks2 * 32 + fk];
        O[nt] = __builtin_amdgcn_mfma_f32_16x16x32_bf16(pa, vb, O[nt], 0, 0, 0);
      }
    }
    #pragma unroll
    for (int nt = 0; nt < 4; ++nt)
      #pragma unroll
      for (int i = 0; i < 4; ++i)
        o[(size_t)(b * S_LEN + qbase + i) * QSZ + (h0 + 1) * DH + nt * 16 + fr] =
            f2bf(O[nt][i] * inv1[i]);
  }
}

extern "C" void kernel_launch(void* const* d_in, const int* in_sizes, int n_in,
                              void* d_out, int out_size, void* d_ws, size_t ws_size,
                              hipStream_t stream) {
  const float* hidden    = (const float*)d_in[0];
  const int*   positions = (const int*)d_in[1];
  const float* Wq = (const float*)d_in[2];
  const float* bq = (const float*)d_in[3];
  const float* Wk = (const float*)d_in[4];
  const float* bk = (const float*)d_in[5];
  const float* Wv = (const float*)d_in[6];
  const float* bv = (const float*)d_in[7];
  const float* Wo = (const float*)d_in[8];
  const float* bo = (const float*)d_in[9];
  float* out = (float*)d_out;

  // workspace:
  //   hbf   [2048][2880] bf16        @ 0          (11,796,480)
  //   WqkvT [5120][2880] bf16        @ 11796480   -- later WoT [2944][4096]
  //   q/o   [2048][4096] bf16        @ 41287680
  //   k     [2048][512]  bf16        @ 58064896
  //   vT    [512][2048]  bf16        @ 60162048
  char* ws = (char*)d_ws;
  unsigned short* hbf   = (unsigned short*)(ws);
  unsigned short* WqkvT = (unsigned short*)(ws + 11796480);
  unsigned short* qb    = (unsigned short*)(ws + 41287680);
  unsigned short* kb    = (unsigned short*)(ws + 58064896);
  unsigned short* vTb   = (unsigned short*)(ws + 60162048);

  prep_kernel<<<dim3(NB_CONV + NB_WQ + 2 * NB_WK), dim3(256), 0, stream>>>(
      hidden, hbf, Wq, Wk, Wv, WqkvT);

  gemm_qkv<<<dim3(NQKV / 128, T_TOK / 64), dim3(128), 0, stream>>>(
      hbf, WqkvT, bq, bk, bv, positions, qb, kb, vTb);

  // WoT (2944 padded rows) overwrites WqkvT after QKV GEMM consumed it
  transpose_w<<<dim3(NOPAD / 64, QSZ / 32), dim3(256), 0, stream>>>(
      Wo, WqkvT, QSZ, HIDN);

  attn_kernel<<<dim3(S_LEN / 64, NHQ / 2, 2), dim3(256), 0, stream>>>(
      qb, kb, vTb, qb);
  gemm_o<<<dim3(NOPAD / 128, T_TOK / 64), dim3(128), 0, stream>>>(
      qb, WqkvT, bo, out);
}